// Round 5
// baseline (5945.824 us; speedup 1.0000x reference)
//
#include <hip/hip_runtime.h>
#include <stdint.h>

#define T_SEQ 512
#define BATCH 256
#define HID   128
#define G4    512   // 4*H
#define XD    257
#define ZD    16

// ---------- helpers ----------
__device__ __forceinline__ float bf2f(uint16_t u) {
  union { uint32_t i; float f; } v; v.i = ((uint32_t)u) << 16; return v.f;
}
__device__ __forceinline__ uint16_t f2bf(float f) {
  union { float f; uint32_t i; } v; v.f = f;
  uint32_t r = v.i + 0x7fffu + ((v.i >> 16) & 1u);
  return (uint16_t)(r >> 16);
}
__device__ __forceinline__ float tanhfast(float x) { return 2.0f / (1.0f + __expf(-2.0f * x)) - 1.0f; }
// unified gate activation: gate 2 -> tanh, else sigmoid (no divergence)
__device__ __forceinline__ float gate_act(float pre, bool isg) {
  float s = isg ? (-2.0f * pre) : (-pre);
  float r = 1.0f / (1.0f + __expf(s));
  return isg ? (2.0f * r - 1.0f) : r;
}

// Pin a value into a VGPR (opaque def: no remat of the feeding load).
#define PIN(x) asm volatile("" : "+v"(x))

// DPP quad_perm cross-lane (VALU pipe): ctrl = sel0|sel1<<2|sel2<<4|sel3<<6
template <int C>
__device__ __forceinline__ float dppq(float x) {
  return __int_as_float(__builtin_amdgcn_mov_dpp(__float_as_int(x), C, 0xF, 0xF, true));
}
// ds_swizzle xor (LDS pipe) for xor masks that cross quads (within 32-lane groups)
template <int O>
__device__ __forceinline__ float swzx(float x) {
  return __int_as_float(__builtin_amdgcn_ds_swizzle(__float_as_int(x), O));
}

// quad transpose-reduce: lane q of each aligned quad gets sum over the quad's 4
// lanes of partial a_q. 3 DPP ops, VALU only.
__device__ __forceinline__ float quad_reduce4(float a0, float a1, float a2, float a3, int g) {
  bool lb = (g & 1) != 0;
  float rl = dppq<0xB1>(lb ? a0 : a1);   // xor1
  float rh = dppq<0xB1>(lb ? a2 : a3);
  float bl = (lb ? a1 : a0) + rl;
  float bh = (lb ? a3 : a2) + rh;
  bool hb = (g & 2) != 0;
  float r2 = dppq<0x4E>(hb ? bl : bh);   // xor2
  return (hb ? bh : bl) + r2;
}

// ---------- kernel 1: weight transposes ----------
__global__ void k_prep(const float* __restrict__ Wih_gx, const float* __restrict__ Wy,
                       float* __restrict__ wT, float* __restrict__ wyT) {
  int idx = blockIdx.x * 256 + threadIdx.x;
  const int N1 = XD * G4;          // 131584
  const int N2 = HID * XD;         // 32896
  if (idx < N1) {
    int j = idx & (G4 - 1), d = idx >> 9;       // wT[d*512+j] = Wih_gx[j*257+d]
    wT[idx] = Wih_gx[j * XD + d];
  } else if (idx < N1 + N2) {
    int i2 = idx - N1;
    int u = i2 / XD, d = i2 % XD;               // wyT[u*257+d] = Wy[d*128+u]
    wyT[i2] = Wy[d * HID + u];
  }
}

// ---------- kernel 2: px[t][b][j] = b_ih+b_hh + sum_d x[b][d][t]*Wih_gx[j][d] (bf16 out) ----------
__global__ __launch_bounds__(256) void k_proj(
    const float* __restrict__ x, const float* __restrict__ wT,
    const float* __restrict__ bih, const float* __restrict__ bhh,
    uint16_t* __restrict__ px) {
  __shared__ uint16_t xs[XD * 66];
  int tid = threadIdx.x;
  int t0 = blockIdx.x * 64, b = blockIdx.y;
  int lane = tid & 63;
  {
    int t = tid & 63, d0 = tid >> 6;
    for (int d = d0; d < XD; d += 4)
      xs[d * 66 + t] = f2bf(x[((size_t)b * XD + d) * T_SEQ + t0 + t]);
  }
  __syncthreads();
  int w = __builtin_amdgcn_readfirstlane(tid >> 6);
  for (int p = 0; p < 8; ++p) {
    int j0 = w * 128 + p * 16;
    float acc[16];
#pragma unroll
    for (int i = 0; i < 16; ++i) acc[i] = bih[j0 + i] + bhh[j0 + i];
    for (int d = 0; d < XD; ++d) {
      float xv = bf2f(xs[d * 66 + lane]);
      const float* wrow = wT + (size_t)d * G4 + j0;
#pragma unroll
      for (int i = 0; i < 16; ++i) acc[i] = fmaf(wrow[i], xv, acc[i]);
    }
    size_t base = ((size_t)(t0 + lane) * BATCH + b) * G4 + j0;
    uint32_t pk[8];
#pragma unroll
    for (int i = 0; i < 8; ++i)
      pk[i] = (uint32_t)f2bf(acc[2 * i]) | ((uint32_t)f2bf(acc[2 * i + 1]) << 16);
    uint4* dst = (uint4*)(px + base);
    dst[0] = make_uint4(pk[0], pk[1], pk[2], pk[3]);
    dst[1] = make_uint4(pk[4], pk[5], pk[6], pk[7]);
  }
}

// ---------- kernel 3: backward LSTM g_x — 1024 thr, 8-slice, ~70 regs/thread ----------
// thread (u = tid>>3, s = tid&7): all 4 gates of unit u over h-slice [s*16, s*16+16).
// Weight share 64 floats/thread -> fits the 128-VGPR cap a 1024-thr block imposes.
__global__ __launch_bounds__(1024) void k_lstm_gx(
    const uint16_t* __restrict__ px, const float* __restrict__ Whh,
    uint16_t* __restrict__ gx) {
  __shared__ __align__(128) float hl[2][HID];
  int tid = threadIdx.x, b = blockIdx.x;
  int u = tid >> 3, s = tid & 7, g = s & 3;
  int j = g * HID + u;                 // gate row for px lookup
  // wA[q][4n+c] = Whh[(q*128+u)*128 + s*16 + ((n+s)&3)*4 + c]  (read-order storage)
  float wA[4][16];
#pragma unroll
  for (int q = 0; q < 4; ++q)
#pragma unroll
    for (int n = 0; n < 4; ++n) {
      int p = (n + s) & 3;
      float4 wv = *(const float4*)(Whh + ((size_t)(q * HID + u)) * HID + s * 16 + p * 4);
      wA[q][4 * n + 0] = wv.x; wA[q][4 * n + 1] = wv.y;
      wA[q][4 * n + 2] = wv.z; wA[q][4 * n + 3] = wv.w;
    }
#pragma unroll
  for (int q = 0; q < 4; ++q)
#pragma unroll
    for (int i = 0; i < 16; ++i) PIN(wA[q][i]);
  if (tid < HID) hl[0][tid] = 0.0f;
  float c = 0.0f;
  int cur = 0;
  bool isg = (g == 2);
  uint16_t pcur = px[((size_t)(T_SEQ - 1) * BATCH + b) * G4 + j];
  __syncthreads();
  for (int t = T_SEQ - 1; t >= 0; --t) {
    int tn = t > 0 ? t - 1 : 0;
    uint16_t pnext = px[((size_t)tn * BATCH + b) * G4 + j];
    const float4* h4 = (const float4*)hl[cur];
    float a0 = 0.f, a1 = 0.f, a2 = 0.f, a3 = 0.f;
#pragma unroll
    for (int n = 0; n < 4; ++n) {
      float4 hv = h4[s * 4 + ((n + s) & 3)];
      a0 = fmaf(wA[0][4 * n + 0], hv.x, a0); a0 = fmaf(wA[0][4 * n + 1], hv.y, a0);
      a0 = fmaf(wA[0][4 * n + 2], hv.z, a0); a0 = fmaf(wA[0][4 * n + 3], hv.w, a0);
      a1 = fmaf(wA[1][4 * n + 0], hv.x, a1); a1 = fmaf(wA[1][4 * n + 1], hv.y, a1);
      a1 = fmaf(wA[1][4 * n + 2], hv.z, a1); a1 = fmaf(wA[1][4 * n + 3], hv.w, a1);
      a2 = fmaf(wA[2][4 * n + 0], hv.x, a2); a2 = fmaf(wA[2][4 * n + 1], hv.y, a2);
      a2 = fmaf(wA[2][4 * n + 2], hv.z, a2); a2 = fmaf(wA[2][4 * n + 3], hv.w, a2);
      a3 = fmaf(wA[3][4 * n + 0], hv.x, a3); a3 = fmaf(wA[3][4 * n + 1], hv.y, a3);
      a3 = fmaf(wA[3][4 * n + 2], hv.z, a3); a3 = fmaf(wA[3][4 * n + 3], hv.w, a3);
    }
    float pre = quad_reduce4(a0, a1, a2, a3, g);
    pre += swzx<0x101F>(pre);            // combine the two quads (xor4)
    pre += bf2f(pcur);
    float act = gate_act(pre, isg);
    float af = dppq<0x55>(act);
    float ag = dppq<0xAA>(act);
    float ao = dppq<0xFF>(act);
    if (g == 0) {                        // lanes s==0 and s==4 keep identical c
      c = af * c + act * ag;
      float h = ao * tanhfast(c);
      if (s == 0) {
        hl[cur ^ 1][u] = h;
        gx[((size_t)t * BATCH + b) * HID + u] = f2bf(h);
      }
    }
    cur ^= 1;
    pcur = pnext;
    __syncthreads();
  }
}

// ---------- kernel 4: fused inference — 1024 thr, slice-split stages ----------
__global__ __launch_bounds__(1024) void k_inf(
    const uint16_t* __restrict__ gx, const float* __restrict__ eps,
    const float* __restrict__ Wih_gz, const float* __restrict__ Whh_gz,
    const float* __restrict__ bih_gz, const float* __restrict__ bhh_gz,
    const float* __restrict__ W0, const float* __restrict__ b0,
    const float* __restrict__ Wm, const float* __restrict__ bm,
    const float* __restrict__ Wv, const float* __restrict__ bv,
    float* __restrict__ zbuf, float* __restrict__ out_mean,
    float* __restrict__ out_logvar, float* __restrict__ out_z) {
  __shared__ __align__(128) float gxl[HID];
  __shared__ __align__(128) float gzl[2][HID];
  __shared__ __align__(128) float hvec[16 * 12];   // h[8m+k] at [12m+k] (bank-spread)
  __shared__ __align__(128) float zl[ZD];
  int tid = threadIdx.x, b = blockIdx.x;
  // ---- stage A layout: (u = tid>>3, s = tid&7), slice = z[s*2,+2) ++ h[s*16,+16) ----
  int u = tid >> 3, s = tid & 7, g = s & 3;
  int j = g * HID + u;
  float wA[4][16];
  float2 wz[4];
#pragma unroll
  for (int q = 0; q < 4; ++q) {
#pragma unroll
    for (int n = 0; n < 4; ++n) {
      int p = (n + s) & 3;
      float4 wv = *(const float4*)(Whh_gz + ((size_t)(q * HID + u)) * HID + s * 16 + p * 4);
      wA[q][4 * n + 0] = wv.x; wA[q][4 * n + 1] = wv.y;
      wA[q][4 * n + 2] = wv.z; wA[q][4 * n + 3] = wv.w;
    }
    wz[q] = *(const float2*)(Wih_gz + (size_t)(q * HID + u) * ZD + s * 2);
  }
#pragma unroll
  for (int q = 0; q < 4; ++q) {
#pragma unroll
    for (int i = 0; i < 16; ++i) PIN(wA[q][i]);
    PIN(wz[q].x); PIN(wz[q].y);
  }
  float bzr = bih_gz[j] + bhh_gz[j];
  // ---- stage B layout: 1 output u per thread, input slice [s*32, s*32+32) of [gx|gz] ----
  float w0r[32];
#pragma unroll
  for (int n = 0; n < 8; ++n) {
    int p = (n + s) & 7;
    float4 va = *(const float4*)(W0 + (size_t)u * 256 + s * 32 + p * 4);
    w0r[4 * n + 0] = va.x; w0r[4 * n + 1] = va.y;
    w0r[4 * n + 2] = va.z; w0r[4 * n + 3] = va.w;
  }
#pragma unroll
  for (int i = 0; i < 32; ++i) PIN(w0r[i]);
  float b0r = b0[u];
  // ---- stage C layout (waves 0-7 only): 32 lanes per o; lanes 0-15 mean, 16-31 logvar ----
  bool loC = tid < 512;
  int o = (tid >> 5) & 15, lo = tid & 31;
  float wmr[8] = {0, 0, 0, 0, 0, 0, 0, 0};
  float bmr = 0.f, bvr = 0.f, epcur = 0.f;
  if (loC) {
    const float* Wsel = (lo < 16) ? (Wm + (size_t)o * HID + (lo & 15) * 8)
                                  : (Wv + (size_t)o * HID + (lo & 15) * 8);
#pragma unroll
    for (int i = 0; i < 8; ++i) wmr[i] = Wsel[i];
    bmr = bm[o]; bvr = bv[o];
    if (lo == 0) epcur = eps[(size_t)b * ZD + o];
  }
  float czr = 0.0f;
  int cur = 0;
  bool isg = (g == 2);
  if (tid < HID) {
    gzl[0][tid] = 0.0f;
    gxl[tid] = bf2f(gx[(size_t)b * HID + tid]);
  }
  __syncthreads();
  for (int t = 0; t < T_SEQ; ++t) {
    int tn = (t < T_SEQ - 1) ? t + 1 : t;
    float gxnext = (tid < HID) ? bf2f(gx[((size_t)tn * BATCH + b) * HID + tid]) : 0.0f;
    float epnext = (loC && lo == 0) ? eps[((size_t)tn * BATCH + b) * ZD + o] : 0.0f;
    // ---- stage B: h = tanh([gx, gz] @ W0.T + b0), 8-slice + 8-lane all-reduce ----
    {
      const float4* seg = (s < 4) ? ((const float4*)gxl + s * 8)
                                  : ((const float4*)(gzl[cur]) + (s - 4) * 8);
      float pa = 0.f;
#pragma unroll
      for (int n = 0; n < 8; ++n) {
        float4 v = seg[(n + s) & 7];
        pa = fmaf(w0r[4 * n + 0], v.x, pa); pa = fmaf(w0r[4 * n + 1], v.y, pa);
        pa = fmaf(w0r[4 * n + 2], v.z, pa); pa = fmaf(w0r[4 * n + 3], v.w, pa);
      }
      pa += dppq<0xB1>(pa); pa += dppq<0x4E>(pa); pa += swzx<0x101F>(pa);
      if (s == 0) hvec[(u >> 3) * 12 + (u & 7)] = tanhfast(pa + b0r);
    }
    __syncthreads();  // b1
    // ---- stage C: mean/logvar/z fused (waves 0-7; wave-uniform branch) ----
    if (loC) {
      int m = lo & 15;
      const float4* hh = (const float4*)(hvec + m * 12);
      float4 h0 = hh[0], h1 = hh[1];
      float p = wmr[0] * h0.x + wmr[1] * h0.y + wmr[2] * h0.z + wmr[3] * h0.w +
                wmr[4] * h1.x + wmr[5] * h1.y + wmr[6] * h1.z + wmr[7] * h1.w;
      p += dppq<0xB1>(p);
      p += dppq<0x4E>(p);
      p += swzx<0x101F>(p);
      p += swzx<0x201F>(p);
      float other = swzx<0x401F>(p);   // lanes 0-15 get logvar sum, 16-31 get mean sum
      if (lo == 0) {
        float mean = p + bmr;
        float lv = other + bvr;
        float zv = epcur * __expf(0.5f * lv) + mean;
        zl[o] = zv;
        out_mean[((size_t)b * ZD + o) * T_SEQ + t] = mean;
        out_logvar[((size_t)b * ZD + o) * T_SEQ + t] = lv;
        out_z[((size_t)b * ZD + o) * T_SEQ + t] = zv;
        zbuf[((size_t)t * BATCH + b) * ZD + o] = zv;
      }
    }
    __syncthreads();  // b2
    // ---- stage A: g_z LSTM cell, 8-slice + quad transpose-reduce + xor4 ----
    {
      float2 zz = *(const float2*)(zl + s * 2);
      float a0 = fmaf(wz[0].y, zz.y, wz[0].x * zz.x);
      float a1 = fmaf(wz[1].y, zz.y, wz[1].x * zz.x);
      float a2 = fmaf(wz[2].y, zz.y, wz[2].x * zz.x);
      float a3 = fmaf(wz[3].y, zz.y, wz[3].x * zz.x);
      const float4* h4 = (const float4*)gzl[cur];
#pragma unroll
      for (int n = 0; n < 4; ++n) {
        float4 hv = h4[s * 4 + ((n + s) & 3)];
        a0 = fmaf(wA[0][4 * n + 0], hv.x, a0); a0 = fmaf(wA[0][4 * n + 1], hv.y, a0);
        a0 = fmaf(wA[0][4 * n + 2], hv.z, a0); a0 = fmaf(wA[0][4 * n + 3], hv.w, a0);
        a1 = fmaf(wA[1][4 * n + 0], hv.x, a1); a1 = fmaf(wA[1][4 * n + 1], hv.y, a1);
        a1 = fmaf(wA[1][4 * n + 2], hv.z, a1); a1 = fmaf(wA[1][4 * n + 3], hv.w, a1);
        a2 = fmaf(wA[2][4 * n + 0], hv.x, a2); a2 = fmaf(wA[2][4 * n + 1], hv.y, a2);
        a2 = fmaf(wA[2][4 * n + 2], hv.z, a2); a2 = fmaf(wA[2][4 * n + 3], hv.w, a2);
        a3 = fmaf(wA[3][4 * n + 0], hv.x, a3); a3 = fmaf(wA[3][4 * n + 1], hv.y, a3);
        a3 = fmaf(wA[3][4 * n + 2], hv.z, a3); a3 = fmaf(wA[3][4 * n + 3], hv.w, a3);
      }
      float pre = quad_reduce4(a0, a1, a2, a3, g);
      pre += swzx<0x101F>(pre);
      pre += bzr;
      float act = gate_act(pre, isg);
      float af = dppq<0x55>(act);
      float ag = dppq<0xAA>(act);
      float ao = dppq<0xFF>(act);
      if (g == 0) {
        czr = af * czr + act * ag;
        float h = ao * tanhfast(czr);
        if (s == 0) gzl[cur ^ 1][u] = h;
      }
      if (tid < HID) gxl[tid] = gxnext;
    }
    epcur = epnext;
    cur ^= 1;
    __syncthreads();  // b3
  }
}

// ---------- kernel 5: decoder LSTM — 1024 thr, 8-slice ----------
__global__ __launch_bounds__(1024) void k_dec(
    const float* __restrict__ zbuf, const float* __restrict__ Wih_h,
    const float* __restrict__ Whh_h, const float* __restrict__ bih,
    const float* __restrict__ bhh, uint16_t* __restrict__ hdec) {
  __shared__ __align__(128) float hl[2][HID];
  __shared__ __align__(128) float zls[2][ZD];
  int tid = threadIdx.x, b = blockIdx.x;
  int u = tid >> 3, s = tid & 7, g = s & 3;
  int j = g * HID + u;
  float wA[4][16];
  float2 wz[4];
#pragma unroll
  for (int q = 0; q < 4; ++q) {
#pragma unroll
    for (int n = 0; n < 4; ++n) {
      int p = (n + s) & 3;
      float4 wv = *(const float4*)(Whh_h + ((size_t)(q * HID + u)) * HID + s * 16 + p * 4);
      wA[q][4 * n + 0] = wv.x; wA[q][4 * n + 1] = wv.y;
      wA[q][4 * n + 2] = wv.z; wA[q][4 * n + 3] = wv.w;
    }
    wz[q] = *(const float2*)(Wih_h + (size_t)(q * HID + u) * ZD + s * 2);
  }
#pragma unroll
  for (int q = 0; q < 4; ++q) {
#pragma unroll
    for (int i = 0; i < 16; ++i) PIN(wA[q][i]);
    PIN(wz[q].x); PIN(wz[q].y);
  }
  float bz = bih[j] + bhh[j];
  if (tid < HID) hl[0][tid] = 0.0f;
  if (tid < ZD) zls[0][tid] = zbuf[(size_t)b * ZD + tid];
  float c = 0.0f;
  int cur = 0;
  bool isg = (g == 2);
  __syncthreads();
  for (int t = 0; t < T_SEQ; ++t) {
    int tn = (t < T_SEQ - 1) ? t + 1 : t;
    float znext = (tid < ZD) ? zbuf[((size_t)tn * BATCH + b) * ZD + tid] : 0.0f;
    float2 zz = *(const float2*)(zls[cur] + s * 2);
    float a0 = fmaf(wz[0].y, zz.y, wz[0].x * zz.x);
    float a1 = fmaf(wz[1].y, zz.y, wz[1].x * zz.x);
    float a2 = fmaf(wz[2].y, zz.y, wz[2].x * zz.x);
    float a3 = fmaf(wz[3].y, zz.y, wz[3].x * zz.x);
    const float4* h4 = (const float4*)hl[cur];
#pragma unroll
    for (int n = 0; n < 4; ++n) {
      float4 hv = h4[s * 4 + ((n + s) & 3)];
      a0 = fmaf(wA[0][4 * n + 0], hv.x, a0); a0 = fmaf(wA[0][4 * n + 1], hv.y, a0);
      a0 = fmaf(wA[0][4 * n + 2], hv.z, a0); a0 = fmaf(wA[0][4 * n + 3], hv.w, a0);
      a1 = fmaf(wA[1][4 * n + 0], hv.x, a1); a1 = fmaf(wA[1][4 * n + 1], hv.y, a1);
      a1 = fmaf(wA[1][4 * n + 2], hv.z, a1); a1 = fmaf(wA[1][4 * n + 3], hv.w, a1);
      a2 = fmaf(wA[2][4 * n + 0], hv.x, a2); a2 = fmaf(wA[2][4 * n + 1], hv.y, a2);
      a2 = fmaf(wA[2][4 * n + 2], hv.z, a2); a2 = fmaf(wA[2][4 * n + 3], hv.w, a2);
      a3 = fmaf(wA[3][4 * n + 0], hv.x, a3); a3 = fmaf(wA[3][4 * n + 1], hv.y, a3);
      a3 = fmaf(wA[3][4 * n + 2], hv.z, a3); a3 = fmaf(wA[3][4 * n + 3], hv.w, a3);
    }
    float pre = quad_reduce4(a0, a1, a2, a3, g);
    pre += swzx<0x101F>(pre);
    pre += bz;
    float act = gate_act(pre, isg);
    float af = dppq<0x55>(act);
    float ag = dppq<0xAA>(act);
    float ao = dppq<0xFF>(act);
    if (g == 0) {
      c = af * c + act * ag;
      float h = ao * tanhfast(c);
      if (s == 0) {
        hl[cur ^ 1][u] = h;
        hdec[((size_t)t * BATCH + b) * HID + u] = f2bf(h);
      }
    }
    if (tid < ZD) zls[cur ^ 1][tid] = znext;
    cur ^= 1;
    __syncthreads();
  }
}

// ---------- kernel 6: y = exp(hdec @ Wy.T + by), output (B, 257, T) ----------
__global__ __launch_bounds__(256) void k_y(
    const uint16_t* __restrict__ hdec, const float* __restrict__ wyT,
    const float* __restrict__ by, float* __restrict__ out_y) {
  __shared__ __align__(16) float hl[HID * 65];
  int tid = threadIdx.x;
  int t0 = blockIdx.x * 64, b = blockIdx.y;
  {
    int uu = tid & 127, tg = tid >> 7;
    for (int tt = tg; tt < 64; tt += 2)
      hl[uu * 65 + tt] = bf2f(hdec[((size_t)(t0 + tt) * BATCH + b) * HID + uu]);
  }
  __syncthreads();
  int w = __builtin_amdgcn_readfirstlane(tid >> 6);
  int lane = tid & 63;
  for (int p = 0; p < 4; ++p) {
    int d0 = w * 16 + p * 64;
    float acc[16];
#pragma unroll
    for (int i = 0; i < 16; ++i) acc[i] = by[d0 + i];
    for (int uu = 0; uu < HID; ++uu) {
      float hv = hl[uu * 65 + lane];
      const float* wrow = wyT + (size_t)uu * XD + d0;
#pragma unroll
      for (int i = 0; i < 16; ++i) acc[i] = fmaf(wrow[i], hv, acc[i]);
    }
#pragma unroll
    for (int i = 0; i < 16; ++i)
      out_y[((size_t)b * XD + d0 + i) * T_SEQ + t0 + lane] = __expf(acc[i]);
  }
  if (w == 0) {  // d = 256 tail
    float acc = by[256];
    for (int uu = 0; uu < HID; ++uu)
      acc = fmaf(wyT[(size_t)uu * XD + 256], hl[uu * 65 + lane], acc);
    out_y[((size_t)b * XD + 256) * T_SEQ + t0 + lane] = __expf(acc);
  }
}

extern "C" void kernel_launch(void* const* d_in, const int* in_sizes, int n_in,
                              void* d_out, int out_size, void* d_ws, size_t ws_size,
                              hipStream_t stream) {
  const float* x      = (const float*)d_in[0];
  const float* eps    = (const float*)d_in[1];
  const float* Wih_gx = (const float*)d_in[2];
  const float* Whh_gx = (const float*)d_in[3];
  const float* bih_gx = (const float*)d_in[4];
  const float* bhh_gx = (const float*)d_in[5];
  const float* Wih_gz = (const float*)d_in[6];
  const float* Whh_gz = (const float*)d_in[7];
  const float* bih_gz = (const float*)d_in[8];
  const float* bhh_gz = (const float*)d_in[9];
  const float* W0     = (const float*)d_in[10];
  const float* b0     = (const float*)d_in[11];
  const float* Wm     = (const float*)d_in[12];
  const float* bm     = (const float*)d_in[13];
  const float* Wv     = (const float*)d_in[14];
  const float* bv     = (const float*)d_in[15];
  const float* Wih_h  = (const float*)d_in[16];
  const float* Whh_h  = (const float*)d_in[17];
  const float* bih_h  = (const float*)d_in[18];
  const float* bhh_h  = (const float*)d_in[19];
  const float* Wy     = (const float*)d_in[20];
  const float* by     = (const float*)d_in[21];

  char* ws = (char*)d_ws;
  float*    wT   = (float*)(ws + 0);                       // 257*512 f32   = 526,336 B
  float*    wyT  = (float*)(ws + 526336);                  // 128*257 f32   = 131,584 B
  uint16_t* px   = (uint16_t*)(ws + (1u << 20));           // bf16 T*B*512  = 134,217,728 B
  uint16_t* gx   = (uint16_t*)(ws + 135266304);            // bf16 T*B*128  =  33,554,432 B
  float*    zbuf = (float*)(ws + 168820736);               // f32  T*B*16   =   8,388,608 B
  uint16_t* hdec = (uint16_t*)(ws + 177209344);            // bf16 T*B*128  =  33,554,432 B

  float* out_y      = (float*)d_out;                         // (B,257,T)
  float* out_mean   = out_y + (size_t)BATCH * XD * T_SEQ;    // (B,16,T)
  float* out_logvar = out_mean + (size_t)BATCH * ZD * T_SEQ;
  float* out_z      = out_logvar + (size_t)BATCH * ZD * T_SEQ;

  k_prep<<<dim3(643), dim3(256), 0, stream>>>(Wih_gx, Wy, wT, wyT);
  k_proj<<<dim3(8, 256), dim3(256), 0, stream>>>(x, wT, bih_gx, bhh_gx, px);
  k_lstm_gx<<<dim3(256), dim3(1024), 0, stream>>>(px, Whh_gx, gx);
  k_inf<<<dim3(256), dim3(1024), 0, stream>>>(gx, eps, Wih_gz, Whh_gz, bih_gz, bhh_gz,
                                              W0, b0, Wm, bm, Wv, bv,
                                              zbuf, out_mean, out_logvar, out_z);
  k_dec<<<dim3(256), dim3(1024), 0, stream>>>(zbuf, Wih_h, Whh_h, bih_h, bhh_h, hdec);
  k_y<<<dim3(8, 256), dim3(256), 0, stream>>>(hdec, wyT, by, out_y);
}